// Round 1
// baseline (293.388 us; speedup 1.0000x reference)
//
#include <hip/hip_runtime.h>

// Soft-DTW forward, gamma=0.1, B=128, T=512.
// One block (512 threads) per batch element; thread j owns column j.
// Anti-diagonal wavefront, 2T-1 steps, triple-buffered diagonals in LDS
// (write buf k%3, read k-1 and k-2 buffers -> disjoint within a step ->
// exactly one __syncthreads per step).

constexpr int   T_LEN = 512;
constexpr float BIGF  = 1.0e7f;

__global__ __launch_bounds__(T_LEN) void softdtw_wavefront(
    const float* __restrict__ x, const float* __restrict__ y,
    float* __restrict__ out, float inv_B) {
  __shared__ float ldx[T_LEN];
  __shared__ float b0[T_LEN], b1[T_LEN], b2[T_LEN];

  const int j    = threadIdx.x;
  const int bidx = blockIdx.x;

  // stage x row; keep own y in a register
  ldx[j] = x[bidx * T_LEN + j];
  const float yj = y[bidx * T_LEN + j];
  __syncthreads();

  const float g  = 0.1f;
  const float ig = 10.0f;  // 1/gamma

  float* bc  = b0;  // diagonal k   (written this step)
  float* bp  = b1;  // diagonal k-1
  float* bpp = b2;  // diagonal k-2

  float vprev = 0.0f;  // own value at step k-1 (cell (i-1, j)); guarded by i==0
  float vlast = 0.0f;

  for (int k = 0; k <= 2 * T_LEN - 2; ++k) {
    const int i = k - j;  // row index into D
    if (0 <= i && i < T_LEN) {
      float d = ldx[i] - yj;
      d = d * d;
      // R-ref coords: cell (i+1, j+1) needs top=R[i][j+1], left=R[i+1][j], tl=R[i][j]
      const float top  = (i == 0) ? BIGF : vprev;       // own column, step k-1
      const float left = (j == 0) ? BIGF : bp[j - 1];   // neighbor, step k-1
      float tl;
      if (i == 0)      tl = (j == 0) ? 0.0f : BIGF;
      else             tl = (j == 0) ? BIGF : bpp[j - 1];  // neighbor, step k-2

      // stable softmin: m - g*log(sum exp((m-a)/g))
      const float m = fminf(fminf(top, left), tl);
      const float s = __expf((m - top) * ig) + __expf((m - left) * ig) +
                      __expf((m - tl) * ig);
      const float val = d + m - g * __logf(s);
      bc[j] = val;
      vprev = val;
      vlast = val;
    }
    __syncthreads();
    // rotate: oldest buffer becomes next write target
    float* t = bpp; bpp = bp; bp = bc; bc = t;
  }

  // thread T-1's last value (step 2T-2) is R[T][T] = final_row[:, -1]
  if (j == T_LEN - 1) {
    atomicAdd(out, vlast * inv_B);
  }
}

extern "C" void kernel_launch(void* const* d_in, const int* in_sizes, int n_in,
                              void* d_out, int out_size, void* d_ws, size_t ws_size,
                              hipStream_t stream) {
  const float* x = (const float*)d_in[0];
  const float* y = (const float*)d_in[1];
  float* out     = (float*)d_out;
  const int B    = in_sizes[0] / T_LEN;  // 128

  hipMemsetAsync(out, 0, sizeof(float), stream);  // d_out is poisoned 0xAA each call
  softdtw_wavefront<<<dim3(B), dim3(T_LEN), 0, stream>>>(x, y, out, 1.0f / (float)B);
}

// Round 5
// 234.405 us; speedup vs baseline: 1.2516x; 1.2516x over previous
//
#include <hip/hip_runtime.h>

// Soft-DTW forward, gamma=0.1, B=128, T=512.
// One WAVE (64 lanes) per batch element. Lane l owns columns [8l, 8l+8).
// Lane l processes row-pair (2k, 2k+1) at step s = k + l  (skew 1 step/lane).
// Neighbor boundaries travel via 2 __shfl_up per step (produced at step end,
// consumed >=1 step later -> shuffle latency off the critical path).
// NO __syncthreads in the main loop.
//
// All values are scaled by C1 = 1/(gamma*ln2) so softmin becomes:
//   val' = d' + M - log2(2^(M-top') + 2^(M-tl') + 2^(M-left')),  M = min3
// with d' = (x*sqrt(C1) - y*sqrt(C1))^2. Unscale once at the end.

constexpr int   T_LEN  = 512;
constexpr int   W      = 8;                 // columns per lane
constexpr int   NL     = 64;                // lanes per wave
constexpr int   KSTEPS = T_LEN / 2;         // 256 row-pairs
constexpr int   STEPS  = KSTEPS + NL - 1;   // 319
constexpr float C1     = 14.426950408889634f;  // 1/(gamma*ln2), gamma=0.1
constexpr float RSC    = 0.06931471805599453f; // gamma*ln2 = 1/C1
constexpr float SQC1   = 3.798282565935283f;   // sqrt(C1)
constexpr float BIGS   = 1.0e7f * C1;          // scaled BIG border

#if __has_builtin(__builtin_amdgcn_exp2f)
#define EXP2F(v) __builtin_amdgcn_exp2f(v)
#else
#define EXP2F(v) __exp2f(v)
#endif
#if __has_builtin(__builtin_amdgcn_logf)
#define LOG2F(v) __builtin_amdgcn_logf(v)
#else
#define LOG2F(v) __log2f(v)
#endif

__device__ __forceinline__ float cellf(float d, float top, float tl, float left) {
  const float m1 = fminf(top, tl);
  const float M  = fminf(m1, left);
  const float e1 = EXP2F(M - top);
  const float e2 = EXP2F(M - tl);
  const float e3 = EXP2F(M - left);
  const float lg = LOG2F((e1 + e2) + e3);  // log2
  return (d + M) - lg;
}

__global__ __launch_bounds__(NL) void softdtw_wave(
    const float* __restrict__ x, const float* __restrict__ y,
    float* __restrict__ out, float out_scale) {
  __shared__ float xs[T_LEN];
  const int lane = threadIdx.x;
  const int b    = blockIdx.x;

  // stage pre-scaled x into LDS; keep own y columns (pre-scaled) in registers
#pragma unroll
  for (int t = 0; t < W; ++t)
    xs[lane * W + t] = x[b * T_LEN + lane * W + t] * SQC1;
  float yv[W];
#pragma unroll
  for (int c = 0; c < W; ++c)
    yv[c] = y[b * T_LEN + lane * W + c] * SQC1;
  __syncthreads();  // only barrier in the kernel

  float r[W];  // previous row's values for own columns
#pragma unroll
  for (int c = 0; c < W; ++c) r[c] = BIGS;

  float upA = BIGS, upB = BIGS, upBp = BIGS;  // shuffled neighbor boundaries
  float vA7 = BIGS, vB7 = BIGS;               // own strip's last-column values

  for (int s = 0; s < STEPS; ++s) {
    const int k  = s - lane;                       // local row-pair index
    const int kc = k < 0 ? 0 : (k > KSTEPS - 1 ? KSTEPS - 1 : k);
    const float2 xx = *reinterpret_cast<const float2*>(&xs[2 * kc]);

    const bool  l0    = (lane == 0);
    const float leftA = l0 ? BIGS : upA;  // val(2k,   8l-1)
    const float tlB   = l0 ? BIGS : upA;  // same value
    const float leftB = l0 ? BIGS : upB;  // val(2k+1, 8l-1)
    const float tlA   = (k == 0) ? (l0 ? 0.0f : BIGS)   // R[0][0]=0 / row-0 border
                                 : (l0 ? BIGS : upBp);  // val(2k-1, 8l-1)

    if (0 <= k && k < KSTEPS) {
      const float xa = xx.x, xb = xx.y;
      float vA[W], vB[W];
      float dx;
      // rows A=2k, B=2k+1; interleaved for ILP (B_c needs A_c, A_{c-1}, B_{c-1})
      dx = xa - yv[0]; vA[0] = cellf(dx * dx, r[0], tlA,   leftA);
      dx = xa - yv[1]; vA[1] = cellf(dx * dx, r[1], r[0],  vA[0]);
      dx = xb - yv[0]; vB[0] = cellf(dx * dx, vA[0], tlB,  leftB);
      dx = xa - yv[2]; vA[2] = cellf(dx * dx, r[2], r[1],  vA[1]);
      dx = xb - yv[1]; vB[1] = cellf(dx * dx, vA[1], vA[0], vB[0]);
      dx = xa - yv[3]; vA[3] = cellf(dx * dx, r[3], r[2],  vA[2]);
      dx = xb - yv[2]; vB[2] = cellf(dx * dx, vA[2], vA[1], vB[1]);
      dx = xa - yv[4]; vA[4] = cellf(dx * dx, r[4], r[3],  vA[3]);
      dx = xb - yv[3]; vB[3] = cellf(dx * dx, vA[3], vA[2], vB[2]);
      dx = xa - yv[5]; vA[5] = cellf(dx * dx, r[5], r[4],  vA[4]);
      dx = xb - yv[4]; vB[4] = cellf(dx * dx, vA[4], vA[3], vB[3]);
      dx = xa - yv[6]; vA[6] = cellf(dx * dx, r[6], r[5],  vA[5]);
      dx = xb - yv[5]; vB[5] = cellf(dx * dx, vA[5], vA[4], vB[4]);
      dx = xa - yv[7]; vA[7] = cellf(dx * dx, r[7], r[6],  vA[6]);
      dx = xb - yv[6]; vB[6] = cellf(dx * dx, vA[6], vA[5], vB[5]);
      dx = xb - yv[7]; vB[7] = cellf(dx * dx, vA[7], vA[6], vB[6]);
#pragma unroll
      for (int c = 0; c < W; ++c) r[c] = vB[c];
      vA7 = vA[7];
      vB7 = vB[7];
    }

    // boundary export for lane l+1 (consumed at step s+1 and s+2)
    upBp = upB;
    upA  = __shfl_up(vA7, 1, 64);
    upB  = __shfl_up(vB7, 1, 64);
  }

  // lane 63's vB7 at k=255 is R[512][512]; unscale and accumulate mean
  if (lane == NL - 1) atomicAdd(out, vB7 * out_scale);
}

extern "C" void kernel_launch(void* const* d_in, const int* in_sizes, int n_in,
                              void* d_out, int out_size, void* d_ws, size_t ws_size,
                              hipStream_t stream) {
  const float* x = (const float*)d_in[0];
  const float* y = (const float*)d_in[1];
  float* out     = (float*)d_out;
  const int B    = in_sizes[0] / T_LEN;  // 128

  hipMemsetAsync(out, 0, sizeof(float), stream);  // d_out is re-poisoned each call
  softdtw_wave<<<dim3(B), dim3(NL), 0, stream>>>(x, y, out, RSC / (float)B);
}

// Round 13
// 233.748 us; speedup vs baseline: 1.2552x; 1.0028x over previous
//
#include <hip/hip_runtime.h>

// Soft-DTW forward, gamma=0.1, B=128, T=512 — LOG-DOMAIN (round-5 math,
// which passed with absmax 0.0) + two perf fixes:
//   1. __launch_bounds__(64, 1): round 5 compiled at 24 VGPRs (8-wave
//      occupancy target) which serialized the A/B exp chains.
//   2. software-pipelined LDS prefetch of the x row-pair.
// One WAVE per batch element; lane l owns columns [8l,8l+8), processes
// row-pair (2k,2k+1) at step s=k+l. Boundaries via 2 shuffles/step,
// consumed >=1 step later. No barriers in the main loop.
// Values scaled by C1 = 1/(gamma*ln2): softmin = M - log2(sum 2^(M-a')),
// d' = (x*sqrt(C1) - y*sqrt(C1))^2; unscale once at the end.

constexpr int   T_LEN  = 512;
constexpr int   W      = 8;                 // columns per lane
constexpr int   NL     = 64;                // lanes per wave
constexpr int   KSTEPS = T_LEN / 2;         // 256 row-pairs
constexpr int   STEPS  = KSTEPS + NL - 1;   // 319
constexpr float C1     = 14.426950408889634f;  // 1/(gamma*ln2), gamma=0.1
constexpr float RSC    = 0.06931471805599453f; // gamma*ln2 = 1/C1
constexpr float SQC1   = 3.798282565935283f;   // sqrt(C1)
constexpr float BIGS   = 1.0e7f * C1;          // scaled BIG border

#if __has_builtin(__builtin_amdgcn_exp2f)
#define EXP2F(v) __builtin_amdgcn_exp2f(v)
#else
#define EXP2F(v) __exp2f(v)
#endif
#if __has_builtin(__builtin_amdgcn_logf)
#define LOG2F(v) __builtin_amdgcn_logf(v)
#else
#define LOG2F(v) __log2f(v)
#endif

__device__ __forceinline__ float cellf(float d, float top, float tl, float left) {
  const float m1 = fminf(top, tl);
  const float M  = fminf(m1, left);
  const float e1 = EXP2F(M - top);
  const float e2 = EXP2F(M - tl);
  const float e3 = EXP2F(M - left);
  const float lg = LOG2F((e1 + e2) + e3);  // log2
  return (d + M) - lg;
}

__global__ __launch_bounds__(NL, 1) void softdtw_wave(
    const float* __restrict__ x, const float* __restrict__ y,
    float* __restrict__ out, float out_scale) {
  __shared__ float xs[T_LEN];
  const int lane = threadIdx.x;
  const int b    = blockIdx.x;

  // stage pre-scaled x into LDS; keep own y columns (pre-scaled) in registers
#pragma unroll
  for (int t = 0; t < W; ++t)
    xs[lane * W + t] = x[b * T_LEN + lane * W + t] * SQC1;
  float yv[W];
#pragma unroll
  for (int c = 0; c < W; ++c)
    yv[c] = y[b * T_LEN + lane * W + c] * SQC1;
  __syncthreads();  // only barrier in the kernel

  float r[W];  // previous row's values for own columns
#pragma unroll
  for (int c = 0; c < W; ++c) r[c] = BIGS;

  float upA = BIGS, upB = BIGS, upBp = BIGS;  // shuffled neighbor boundaries
  float vA7 = BIGS, vB7 = BIGS;               // own strip's last-column values

  // prefetch row-pair for step 0
  int kc0 = 0 - lane; kc0 = kc0 < 0 ? 0 : kc0;
  float2 xx = *reinterpret_cast<const float2*>(&xs[2 * kc0]);

  for (int s = 0; s < STEPS; ++s) {
    const int k = s - lane;  // local row-pair index
    // prefetch next step's row pair (off critical path)
    int kn = s + 1 - lane;
    kn = kn < 0 ? 0 : (kn > KSTEPS - 1 ? KSTEPS - 1 : kn);
    const float2 xxn = *reinterpret_cast<const float2*>(&xs[2 * kn]);

    const bool  l0    = (lane == 0);
    const float leftA = l0 ? BIGS : upA;  // val(2k,   8l-1)
    const float tlB   = l0 ? BIGS : upA;  // same value
    const float leftB = l0 ? BIGS : upB;  // val(2k+1, 8l-1)
    const float tlA   = (k == 0) ? (l0 ? 0.0f : BIGS)   // R[0][0]=0 / row-0 border
                                 : (l0 ? BIGS : upBp);  // val(2k-1, 8l-1)

    if (0 <= k && k < KSTEPS) {
      const float xa = xx.x, xb = xx.y;
      float vA[W], vB[W];
      float dx;
      // rows A=2k, B=2k+1; interleaved for ILP (B_c needs A_c, A_{c-1}, B_{c-1})
      dx = xa - yv[0]; vA[0] = cellf(dx * dx, r[0], tlA,   leftA);
      dx = xa - yv[1]; vA[1] = cellf(dx * dx, r[1], r[0],  vA[0]);
      dx = xb - yv[0]; vB[0] = cellf(dx * dx, vA[0], tlB,  leftB);
      dx = xa - yv[2]; vA[2] = cellf(dx * dx, r[2], r[1],  vA[1]);
      dx = xb - yv[1]; vB[1] = cellf(dx * dx, vA[1], vA[0], vB[0]);
      dx = xa - yv[3]; vA[3] = cellf(dx * dx, r[3], r[2],  vA[2]);
      dx = xb - yv[2]; vB[2] = cellf(dx * dx, vA[2], vA[1], vB[1]);
      dx = xa - yv[4]; vA[4] = cellf(dx * dx, r[4], r[3],  vA[3]);
      dx = xb - yv[3]; vB[3] = cellf(dx * dx, vA[3], vA[2], vB[2]);
      dx = xa - yv[5]; vA[5] = cellf(dx * dx, r[5], r[4],  vA[4]);
      dx = xb - yv[4]; vB[4] = cellf(dx * dx, vA[4], vA[3], vB[3]);
      dx = xa - yv[6]; vA[6] = cellf(dx * dx, r[6], r[5],  vA[5]);
      dx = xb - yv[5]; vB[5] = cellf(dx * dx, vA[5], vA[4], vB[4]);
      dx = xa - yv[7]; vA[7] = cellf(dx * dx, r[7], r[6],  vA[6]);
      dx = xb - yv[6]; vB[6] = cellf(dx * dx, vA[6], vA[5], vB[5]);
      dx = xb - yv[7]; vB[7] = cellf(dx * dx, vA[7], vA[6], vB[6]);
#pragma unroll
      for (int c = 0; c < W; ++c) r[c] = vB[c];
      vA7 = vA[7];
      vB7 = vB[7];
    }

    // boundary export for lane l+1 (consumed at step s+1 and s+2)
    upBp = upB;
    upA  = __shfl_up(vA7, 1, 64);
    upB  = __shfl_up(vB7, 1, 64);
    xx   = xxn;
  }

  // lane 63's vB7 at k=255 is R[512][512]; unscale and accumulate mean
  if (lane == NL - 1) {
    atomicAdd(out, vB7 * out_scale);
  }
}

extern "C" void kernel_launch(void* const* d_in, const int* in_sizes, int n_in,
                              void* d_out, int out_size, void* d_ws, size_t ws_size,
                              hipStream_t stream) {
  const float* x = (const float*)d_in[0];
  const float* y = (const float*)d_in[1];
  float* out     = (float*)d_out;
  const int B    = in_sizes[0] / T_LEN;  // 128

  hipMemsetAsync(out, 0, sizeof(float), stream);  // d_out re-poisoned each call
  softdtw_wave<<<dim3(B), dim3(NL), 0, stream>>>(x, y, out, RSC / (float)B);
}

// Round 14
// 206.442 us; speedup vs baseline: 1.4212x; 1.1323x over previous
//
#include <hip/hip_runtime.h>

// Soft-DTW forward, gamma=0.1, B=128, T=512 — log-domain (round-13 math,
// absmax 0.0), now TWO WAVES per batch element to double issue width and
// halve the per-step dependence chain (round-13 showed 1 wave is stuck at
// 1390 cy/step vs ~900 issue floor; compiler won't stretch live ranges).
// Global lane g = tid (0..127) owns columns [4g, 4g+4); processes row-pair
// (2k,2k+1) at step s = k + g. Intra-wave boundaries via __shfl_up; the
// wave0->wave1 boundary (g=63 -> g=64) via a parity-buffered LDS slot +
// one __syncthreads per step. Values scaled by C1 = 1/(gamma*ln2):
// softmin = M - log2(sum 2^(M-a')), d' = (x*sqrt(C1)-y*sqrt(C1))^2.

constexpr int   T_LEN  = 512;
constexpr int   W      = 4;                 // columns per lane
constexpr int   G      = 128;               // global lanes (2 waves)
constexpr int   KSTEPS = T_LEN / 2;         // 256 row-pairs
constexpr int   STEPS  = KSTEPS + G - 1;    // 383
constexpr float C1     = 14.426950408889634f;  // 1/(gamma*ln2), gamma=0.1
constexpr float RSC    = 0.06931471805599453f; // gamma*ln2 = 1/C1
constexpr float SQC1   = 3.798282565935283f;   // sqrt(C1)
constexpr float BIGS   = 1.0e7f * C1;          // scaled BIG border

#if __has_builtin(__builtin_amdgcn_exp2f)
#define EXP2F(v) __builtin_amdgcn_exp2f(v)
#else
#define EXP2F(v) __exp2f(v)
#endif
#if __has_builtin(__builtin_amdgcn_logf)
#define LOG2F(v) __builtin_amdgcn_logf(v)
#else
#define LOG2F(v) __log2f(v)
#endif

__device__ __forceinline__ float cellf(float d, float top, float tl, float left) {
  const float m1 = fminf(top, tl);
  const float M  = fminf(m1, left);
  const float e1 = EXP2F(M - top);
  const float e2 = EXP2F(M - tl);
  const float e3 = EXP2F(M - left);
  const float lg = LOG2F((e1 + e2) + e3);  // log2
  return (d + M) - lg;
}

__global__ __launch_bounds__(G, 1) void softdtw_wave2(
    const float* __restrict__ x, const float* __restrict__ y,
    float* __restrict__ out, float out_scale) {
  __shared__ float xs[T_LEN];
  __shared__ float2 xslot[2];  // wave0-lane63 -> wave1-lane0, parity-buffered
  const int g = threadIdx.x;   // global lane 0..127
  const int b = blockIdx.x;

  // stage pre-scaled x into LDS; keep own y columns (pre-scaled) in registers
#pragma unroll
  for (int t = 0; t < W; ++t)
    xs[g * W + t] = x[b * T_LEN + g * W + t] * SQC1;
  float yv[W];
#pragma unroll
  for (int c = 0; c < W; ++c)
    yv[c] = y[b * T_LEN + g * W + c] * SQC1;
  __syncthreads();

  float r[W];  // previous row's values for own columns
#pragma unroll
  for (int c = 0; c < W; ++c) r[c] = BIGS;

  float upA = BIGS, upB = BIGS, upBp = BIGS;  // neighbor boundaries
  float vA3 = BIGS, vB3 = BIGS;               // own strip's last-column values

  // prefetch row-pair for step 0
  int kc0 = 0 - g; kc0 = kc0 < 0 ? 0 : kc0;
  float2 xx = *reinterpret_cast<const float2*>(&xs[2 * kc0]);

  for (int s = 0; s < STEPS; ++s) {
    const int k = s - g;  // local row-pair index
    // prefetch next step's row pair (off critical path)
    int kn = s + 1 - g;
    kn = kn < 0 ? 0 : (kn > KSTEPS - 1 ? KSTEPS - 1 : kn);
    const float2 xxn = *reinterpret_cast<const float2*>(&xs[2 * kn]);

    const bool  l0    = (g == 0);
    const float leftA = l0 ? BIGS : upA;  // val(2k,   4g-1)
    const float tlB   = l0 ? BIGS : upA;  // same value
    const float leftB = l0 ? BIGS : upB;  // val(2k+1, 4g-1)
    const float tlA   = (k == 0) ? (l0 ? 0.0f : BIGS)   // R[0][0]=0 / row-0 border
                                 : (l0 ? BIGS : upBp);  // val(2k-1, 4g-1)

    if (0 <= k && k < KSTEPS) {
      const float xa = xx.x, xb = xx.y;
      float vA[W], vB[W];
      float dx;
      // rows A=2k, B=2k+1; interleaved (B_c needs A_c, A_{c-1}, B_{c-1})
      dx = xa - yv[0]; vA[0] = cellf(dx * dx, r[0], tlA,   leftA);
      dx = xa - yv[1]; vA[1] = cellf(dx * dx, r[1], r[0],  vA[0]);
      dx = xb - yv[0]; vB[0] = cellf(dx * dx, vA[0], tlB,  leftB);
      dx = xa - yv[2]; vA[2] = cellf(dx * dx, r[2], r[1],  vA[1]);
      dx = xb - yv[1]; vB[1] = cellf(dx * dx, vA[1], vA[0], vB[0]);
      dx = xa - yv[3]; vA[3] = cellf(dx * dx, r[3], r[2],  vA[2]);
      dx = xb - yv[2]; vB[2] = cellf(dx * dx, vA[2], vA[1], vB[1]);
      dx = xb - yv[3]; vB[3] = cellf(dx * dx, vA[3], vA[2], vB[2]);
#pragma unroll
      for (int c = 0; c < W; ++c) r[c] = vB[c];
      vA3 = vA[3];
      vB3 = vB[3];
    }

    // cross-wave handoff: g=63 publishes its step-s boundary
    if (g == 63) xslot[s & 1] = make_float2(vA3, vB3);
    upBp = upB;
    // intra-wave boundary (lane l-1's step-s values)
    float nA = __shfl_up(vA3, 1, 64);
    float nB = __shfl_up(vB3, 1, 64);
    __syncthreads();  // orders the xslot write before the read below
    if (g == 64) {
      const float2 v = xslot[s & 1];
      nA = v.x; nB = v.y;
    }
    upA = nA; upB = nB;
    xx = xxn;
  }

  // g=127's vB3 at k=255 is R[512][512]; unscale and accumulate mean
  if (g == G - 1) atomicAdd(out, vB3 * out_scale);
}

extern "C" void kernel_launch(void* const* d_in, const int* in_sizes, int n_in,
                              void* d_out, int out_size, void* d_ws, size_t ws_size,
                              hipStream_t stream) {
  const float* x = (const float*)d_in[0];
  const float* y = (const float*)d_in[1];
  float* out     = (float*)d_out;
  const int B    = in_sizes[0] / T_LEN;  // 128

  hipMemsetAsync(out, 0, sizeof(float), stream);  // d_out re-poisoned each call
  softdtw_wave2<<<dim3(B), dim3(G), 0, stream>>>(x, y, out, RSC / (float)B);
}